// Round 1
// baseline (48.699 us; speedup 1.0000x reference)
//
#include <hip/hip_runtime.h>

#define NBLOCKS 2048
#define NTHREADS 256

__global__ __launch_bounds__(NTHREADS) void pareto_partial(
    const float* __restrict__ y,
    const float* __restrict__ alpha,
    const int* __restrict__ xm_p,
    float* __restrict__ partials,
    int n)
{
    const float xm = (float)xm_p[0];
    const int n4 = n >> 2;
    const float4* __restrict__ y4 = (const float4*)y;
    const float4* __restrict__ a4 = (const float4*)alpha;

    float acc = 0.0f;
    const int stride = gridDim.x * blockDim.x;
    for (int i = blockIdx.x * blockDim.x + threadIdx.x; i < n4; i += stride) {
        float4 yv = y4[i];
        float4 av = a4[i];
        if (yv.x > 0.0f) acc += logf(av.x) * xm - (av.x + 1.0f) * logf(yv.x);
        if (yv.y > 0.0f) acc += logf(av.y) * xm - (av.y + 1.0f) * logf(yv.y);
        if (yv.z > 0.0f) acc += logf(av.z) * xm - (av.z + 1.0f) * logf(yv.z);
        if (yv.w > 0.0f) acc += logf(av.w) * xm - (av.w + 1.0f) * logf(yv.w);
    }

    // tail (n not multiple of 4) — handled by global thread 0
    if (blockIdx.x == 0 && threadIdx.x == 0) {
        for (int i = n4 << 2; i < n; ++i) {
            float yv = y[i];
            if (yv > 0.0f) {
                float av = alpha[i];
                acc += logf(av) * xm - (av + 1.0f) * logf(yv);
            }
        }
    }

    // wave-64 reduction
    #pragma unroll
    for (int off = 32; off > 0; off >>= 1)
        acc += __shfl_down(acc, off, 64);

    __shared__ float wsum[NTHREADS / 64];
    const int lane = threadIdx.x & 63;
    const int wid  = threadIdx.x >> 6;
    if (lane == 0) wsum[wid] = acc;
    __syncthreads();
    if (threadIdx.x == 0) {
        float s = 0.0f;
        #pragma unroll
        for (int w = 0; w < NTHREADS / 64; ++w) s += wsum[w];
        partials[blockIdx.x] = s;
    }
}

__global__ __launch_bounds__(256) void pareto_final(
    const float* __restrict__ partials,
    float* __restrict__ out,
    int nb)
{
    // deterministic fixed-order double accumulation
    double acc = 0.0;
    for (int i = threadIdx.x; i < nb; i += 256)
        acc += (double)partials[i];

    __shared__ double s[256];
    s[threadIdx.x] = acc;
    __syncthreads();
    #pragma unroll
    for (int off = 128; off > 0; off >>= 1) {
        if (threadIdx.x < off) s[threadIdx.x] += s[threadIdx.x + off];
        __syncthreads();
    }
    if (threadIdx.x == 0) out[0] = (float)(-s[0]);
}

extern "C" void kernel_launch(void* const* d_in, const int* in_sizes, int n_in,
                              void* d_out, int out_size, void* d_ws, size_t ws_size,
                              hipStream_t stream)
{
    const float* y     = (const float*)d_in[0];
    const float* alpha = (const float*)d_in[1];
    const int*   xm    = (const int*)d_in[2];
    float* out = (float*)d_out;
    float* partials = (float*)d_ws;   // NBLOCKS floats = 8 KB scratch

    const int n = in_sizes[0];
    int n4 = n >> 2;
    int grid = (n4 + NTHREADS - 1) / NTHREADS;
    if (grid > NBLOCKS) grid = NBLOCKS;
    if (grid < 1) grid = 1;

    pareto_partial<<<grid, NTHREADS, 0, stream>>>(y, alpha, xm, partials, n);
    pareto_final<<<1, 256, 0, stream>>>(partials, out, grid);
}